// Round 13
// baseline (30275.278 us; speedup 1.0000x reference)
//
#include <hip/hip_runtime.h>
#include <hip/hip_bf16.h>

#define HID 1024
#define BATCH 128
#define TSTEPS 512
#define NWG 128
#define NTHR 512

typedef __bf16 bf16x4 __attribute__((ext_vector_type(4)));
typedef __bf16 bf16x8 __attribute__((ext_vector_type(8)));
typedef float f32x4 __attribute__((ext_vector_type(4)));

#define ASTORE_U(p,v) __hip_atomic_store((p),(v),__ATOMIC_RELAXED,__HIP_MEMORY_SCOPE_AGENT)
#define ASTORE_F(p,v) __hip_atomic_store((p),(v),__ATOMIC_RELAXED,__HIP_MEMORY_SCOPE_AGENT)
#define ALOAD_U(p)    __hip_atomic_load((p),__ATOMIC_RELAXED,__HIP_MEMORY_SCOPE_AGENT)
#define ALOAD_F(p)    __hip_atomic_load((p),__ATOMIC_RELAXED,__HIP_MEMORY_SCOPE_AGENT)
#define ALOAD_ULL(p)  __hip_atomic_load((p),__ATOMIC_RELAXED,__HIP_MEMORY_SCOPE_AGENT)
#define AADD_U(p,v)   __hip_atomic_fetch_add((p),(v),__ATOMIC_RELAXED,__HIP_MEMORY_SCOPE_AGENT)

__device__ __forceinline__ float sigm(float x){ return 1.f/(1.f+__expf(-x)); }

__device__ __forceinline__ bf16x8 cvt8(const float* __restrict__ p){
  bf16x8 r;
  #pragma unroll
  for (int i=0;i<8;i++) r[i] = (__bf16)p[i];
  return r;
}
__device__ __forceinline__ bf16x8 cvt8s(const float* __restrict__ p, float s){
  bf16x8 r;
  #pragma unroll
  for (int i=0;i<8;i++) r[i] = (__bf16)(p[i]*s);
  return r;
}

// staging layout (proven): element (u,b) at  (u>>2)*512 + b*4 + (u&3)  [bf16]
__global__ void init_kernel(const float* __restrict__ z,
                            unsigned short* __restrict__ st0,
                            unsigned* __restrict__ bar){
  int i = blockIdx.x*blockDim.x + threadIdx.x;     // 65536 threads
  if (i < 1024) bar[i] = 0u;
  for (int idx = i; idx < BATCH*HID; idx += 65536){
    int blk = idx >> 9, rem = idx & 511, b = rem >> 2, du = rem & 3;
    st0[idx] = __builtin_bit_cast(unsigned short, (__bf16)z[b*HID + blk*4 + du]);
  }
}

// barrier word offsets, each slot in its own 128B line, all < 1024 words (4KB)
#define GRP_CTR(g)  ((g)*32)
#define MID_CTR     256
#define GRP_FLAG(g) (320 + (g)*32)

// 128 WGs x 8 units: halves the per-phase h-broadcast (64MB -> 32MB aggregate)
// to test the aggregate-L3-BW-bound thesis. Weights: Whh0/Whh1 LDS-resident
// (128KB, pre-swizzled B-frags); Wih1 streamed from L2 each phase A (read-only
// -> cacheable, no coherence hazard); Wfold recomputed rank-1 from Wout (4KB,
// L1-hot). Gate K-order identical to round 12 -> bitwise-same h trajectory.
__global__ __launch_bounds__(NTHR, 2) void lstm_kernel(
    const float* __restrict__ seq,
    const float* __restrict__ z,
    const float* __restrict__ Wih0, const float* __restrict__ Whh0,
    const float* __restrict__ bih0, const float* __restrict__ bhh0,
    const float* __restrict__ Wih1, const float* __restrict__ Whh1,
    const float* __restrict__ bih1, const float* __restrict__ bhh1,
    const float* __restrict__ Wout, const float* __restrict__ bout,
    float* __restrict__ out,
    unsigned short* __restrict__ st0,
    unsigned short* __restrict__ st1,
    float* __restrict__ predpart,   // [wg][b]
    float* __restrict__ losspart,
    unsigned* __restrict__ bar)
{
  const int tid  = threadIdx.x;
  const int wg   = blockIdx.x;
  const int wid  = tid >> 6;
  const int lane = tid & 63;
  const int u0   = wg << 3;          // owns units [u0,u0+8) in both layers

  __shared__ bf16x8 wlds[2][2][32][64];  // [mat 0=Whh0,1=Whh1][ct][kt][lane] 128KB
  __shared__ float finals2[32*132];      // [col][b], padded stride 132 (16.9KB)
  __shared__ float pr2[2];
  __shared__ float sb0p[32], sb0f[32], sb1[32];

  const float bout_s = bout[0];

  // bias vectors: col c = gate*8 + unit  (32 cols)
  if (tid < 32) {
    int g = tid >> 3, u = tid & 7;
    int gc = g*HID + u0 + u;
    float bp = bih0[gc] + bhh0[gc];
    sb0p[tid] = bp;                       // layer0 bias, t==0 (pred = 0)
    sb0f[tid] = bp + Wih0[gc]*bout_s;     // layer0 bias + folded b_out term
    sb1[tid]  = bih1[gc] + bhh1[gc];
  }

  // elementwise map: thread -> (batch b, unit-offset edu) handling units edu, edu+4
  const int eb  = tid >> 2;
  const int edu = tid & 3;
  const float woutA = Wout[u0 + edu];
  const float woutB = Wout[u0 + 4 + edu];
  float c0A = z[eb*HID + u0 + edu],     c1A = c0A;
  float c0B = z[eb*HID + u0 + 4 + edu], c1B = c0B;
  float lossacc = 0.f;
  float myfull  = 0.f;                    // thread0: full pred sum for batch wg

  // ---- B-frag row indices: tile ct covers cols [16ct,16ct+16); col=16ct+(lane&15)
  // row into W[4096][*] = gate*1024 + u0 + unit; gcr1 = gcr0 + 2048 (gate+2).
  const int c16  = lane & 15;
  const int gcr0 = (c16 >> 3)*HID + u0 + (c16 & 7);
  const int ksub = (lane >> 4) << 3;
  const float wih0c0 = Wih0[gcr0];
  const float wih0c1 = Wih0[gcr0 + 2048];

  // resident weights -> LDS (each wave loads its 4 kt-slices)
  {
    #pragma unroll
    for (int ktl=0; ktl<4; ++ktl) {
      int ktg = (wid << 2) + ktl;
      int k0  = (ktg << 5) + ksub;
      wlds[0][0][ktg][lane] = cvt8(Whh0 + (size_t)gcr0*HID + k0);
      wlds[0][1][ktg][lane] = cvt8(Whh0 + (size_t)(gcr0+2048)*HID + k0);
      wlds[1][0][ktg][lane] = cvt8(Whh1 + (size_t)gcr0*HID + k0);
      wlds[1][1][ktg][lane] = cvt8(Whh1 + (size_t)(gcr0+2048)*HID + k0);
    }
  }
  __syncthreads();

  f32x4 accG0[2] = {f32x4{0,0,0,0}, f32x4{0,0,0,0}};
  f32x4 accG1[2] = {f32x4{0,0,0,0}, f32x4{0,0,0,0}};
  unsigned gen = 0;

  // A-frag (M-split, proven round-12 addressing): b = wid*16 + (lane&15)
  const int hi2 = (lane >> 4) << 1;
  const int bb4 = ((wid << 4) + c16) << 2;

  auto ldfrag = [&](const unsigned short* __restrict__ src, int kt)->bf16x8{
    const unsigned short* p = src + (size_t)(((kt << 3) + hi2) * 512) + bb4;
    unsigned long long lo64 = ALOAD_ULL((const unsigned long long*)p);
    unsigned long long hi64 = ALOAD_ULL((const unsigned long long*)(p + 512));
    bf16x4 lo = __builtin_bit_cast(bf16x4, lo64);
    bf16x4 hi = __builtin_bit_cast(bf16x4, hi64);
    return __builtin_shufflevector(lo, hi, 0,1,2,3,4,5,6,7);
  };

  // MODE 0 (prologue): both resident (Whh0, Whh1)
  // MODE 1 (phase A): accA <- streamed Wih1 (L2-cached fp32->bf16); accB <- resident Whh0
  // MODE 2 (phase B): accA <- recomputed Wfold (rank-1); accB <- resident Whh1
  auto do_pass = [&](const unsigned short* __restrict__ src, int mode,
                     f32x4* accA, f32x4* accB){
    const float* w1p0 = Wih1 + (size_t)gcr0*HID;
    const float* w1p1 = Wih1 + (size_t)(gcr0+2048)*HID;
    bf16x8 af[8];
    #pragma unroll
    for (int i=0;i<8;i++) af[i] = ldfrag(src, i);
    #pragma unroll
    for (int kt=0; kt<32; ++kt){
      bf16x8 a = af[kt & 7];
      int k0 = (kt << 5) + ksub;
      if (mode == 0) {
        accA[0] = __builtin_amdgcn_mfma_f32_16x16x32_bf16(a, wlds[0][0][kt][lane], accA[0], 0, 0, 0);
        accA[1] = __builtin_amdgcn_mfma_f32_16x16x32_bf16(a, wlds[0][1][kt][lane], accA[1], 0, 0, 0);
        accB[0] = __builtin_amdgcn_mfma_f32_16x16x32_bf16(a, wlds[1][0][kt][lane], accB[0], 0, 0, 0);
        accB[1] = __builtin_amdgcn_mfma_f32_16x16x32_bf16(a, wlds[1][1][kt][lane], accB[1], 0, 0, 0);
      } else if (mode == 1) {
        bf16x8 wf0 = cvt8(w1p0 + k0);
        bf16x8 wf1 = cvt8(w1p1 + k0);
        accA[0] = __builtin_amdgcn_mfma_f32_16x16x32_bf16(a, wf0, accA[0], 0, 0, 0);
        accA[1] = __builtin_amdgcn_mfma_f32_16x16x32_bf16(a, wf1, accA[1], 0, 0, 0);
        accB[0] = __builtin_amdgcn_mfma_f32_16x16x32_bf16(a, wlds[0][0][kt][lane], accB[0], 0, 0, 0);
        accB[1] = __builtin_amdgcn_mfma_f32_16x16x32_bf16(a, wlds[0][1][kt][lane], accB[1], 0, 0, 0);
      } else {
        bf16x8 wf0 = cvt8s(Wout + k0, wih0c0);
        bf16x8 wf1 = cvt8s(Wout + k0, wih0c1);
        accA[0] = __builtin_amdgcn_mfma_f32_16x16x32_bf16(a, wf0, accA[0], 0, 0, 0);
        accA[1] = __builtin_amdgcn_mfma_f32_16x16x32_bf16(a, wf1, accA[1], 0, 0, 0);
        accB[0] = __builtin_amdgcn_mfma_f32_16x16x32_bf16(a, wlds[1][0][kt][lane], accB[0], 0, 0, 0);
        accB[1] = __builtin_amdgcn_mfma_f32_16x16x32_bf16(a, wlds[1][1][kt][lane], accB[1], 0, 0, 0);
      }
      if (kt < 24) af[kt & 7] = ldfrag(src, kt + 8);   // refill after last use
    }
  };

  // acc final (full K per wave): scatter to finals2[col][b] (+bias), one sync.
  // C layout (m89): col=lane&15 within tile, row=(lane>>4)*4+e -> b = wid*16+row.
  auto publish = [&](f32x4* acc, const float* sbias){
    #pragma unroll
    for (int ct=0; ct<2; ++ct){
      int c = (ct << 4) + c16;
      float bias = sbias[c];
      int base = c*132 + (wid << 4) + ((lane >> 4) << 2);
      #pragma unroll
      for (int e=0;e<4;e++) finals2[base + e] = acc[ct][e] + bias;
      acc[ct] = f32x4{0,0,0,0};
    }
    __syncthreads();
  };

  auto elementwise = [&](float& cA, float& cB, unsigned short* __restrict__ stdst,
                         bool dopred){
    // unit uA = edu: cols i=edu, f=8+edu, g=16+edu, o=24+edu
    float giA = finals2[(edu    )*132 + eb];
    float gfA = finals2[(edu+ 8 )*132 + eb];
    float ggA = finals2[(edu+16 )*132 + eb];
    float goA = finals2[(edu+24 )*132 + eb];
    // unit uB = 4+edu
    float giB = finals2[(edu+ 4 )*132 + eb];
    float gfB = finals2[(edu+12 )*132 + eb];
    float ggB = finals2[(edu+20 )*132 + eb];
    float goB = finals2[(edu+28 )*132 + eb];
    cA = sigm(gfA)*cA + sigm(giA)*tanhf(ggA);
    float hA = sigm(goA)*tanhf(cA);
    cB = sigm(gfB)*cB + sigm(giB)*tanhf(ggB);
    float hB = sigm(goB)*tanhf(cB);
    unsigned hA16 = (unsigned)__builtin_bit_cast(unsigned short, (__bf16)hA);
    unsigned hB16 = (unsigned)__builtin_bit_cast(unsigned short, (__bf16)hB);
    unsigned nA = (unsigned)__shfl_xor((int)hA16, 1);
    unsigned nB = (unsigned)__shfl_xor((int)hB16, 1);
    if (!(tid & 1)) {
      unsigned wordA = hA16 | (nA << 16);   // units edu,edu+1 -> block 2wg
      unsigned wordB = hB16 | (nB << 16);   // units 4+edu,5+edu -> block 2wg+1
      ASTORE_U((unsigned*)(stdst + (2*wg  )*512 + eb*4 + edu), wordA);
      ASTORE_U((unsigned*)(stdst + (2*wg+1)*512 + eb*4 + edu), wordB);
    }
    if (dopred){
      float pv = hA*woutA + hB*woutB;
      pv += __shfl_xor(pv, 1);
      pv += __shfl_xor(pv, 2);
      if (edu == 0) ASTORE_F(&predpart[wg*128 + eb], pv);
    }
  };

  // proven barrier (8 groups x 16 WGs): padded counters, fan-out release, sc1.
  auto grid_barrier = [&](){
    __syncthreads();                       // drains vmcnt -> sc1 stores at L3
    ++gen;
    if (tid == 0) {
      unsigned old = AADD_U(&bar[GRP_CTR(wg & 7)], 1u);
      if (old == gen*16u - 1u) {
        unsigned r = AADD_U(&bar[MID_CTR], 1u);
        if (r == gen*8u - 1u) {
          #pragma unroll
          for (int g2=0; g2<8; ++g2) ASTORE_U(&bar[GRP_FLAG(g2)], gen);
        }
      }
      while (ALOAD_U(&bar[GRP_FLAG(wg & 7)]) < gen)
        __builtin_amdgcn_s_sleep(4);
    }
    __syncthreads();
  };

  // ---- prologue: accG0 = z@Whh0 (gates0[0]); accG1 = z@Whh1 (carry) ----
  do_pass(st0, 0, accG0, accG1);
  grid_barrier();                          // all WGs consumed z-staging
  publish(accG0, sb0p);
  elementwise(c0A, c0B, st0, false);       // h0[0] -> st0
  grid_barrier();                          // publish h0[0]

  for (int t=0; t<TSTEPS; ++t) {
    // ---- Phase A: gates1[t] completes (h0@Wih1 streamed); gates0[t+1] h0-part ----
    do_pass(st0, 1, accG1, accG0);
    publish(accG1, sb1);
    if (t > 0 && tid == 0) {               // finalize pred[t-1] (batch wg)
      float pred = myfull + bout_s;
      out[1 + wg*TSTEPS + (t-1)] = pred;
      float d = seq[wg*TSTEPS + (t-1)] - pred;
      lossacc += d*d;
    }
    elementwise(c1A, c1B, st1, true);      // h1[t] + pred partials
    grid_barrier();                        // publish h1[t], predpart

    // ---- Phase B: gates0[t+1] completes (h1@Wfold rank-1); gates1[t+1] h1-part ----
    float hred = 0.f;
    if (tid < 128)
      hred = ALOAD_F(&predpart[tid*128 + wg]);   // early load, all 128 partials
    do_pass(st1, 2, accG0, accG1);
    hred += __shfl_xor(hred, 1);  hred += __shfl_xor(hred, 2);
    hred += __shfl_xor(hred, 4);  hred += __shfl_xor(hred, 8);
    hred += __shfl_xor(hred, 16); hred += __shfl_xor(hred, 32);
    if (tid == 0)  pr2[0] = hred;
    if (tid == 64) pr2[1] = hred;
    publish(accG0, sb0f);                  // internal sync publishes pr2 to tid0
    if (tid == 0) myfull = pr2[0] + pr2[1];
    elementwise(c0A, c0B, st0, false);     // h0[t+1]
    grid_barrier();                        // publish h0[t+1]
  }

  // ---- epilogue: last pred + loss ----
  if (tid == 0) {
    float pred = myfull + bout_s;
    out[1 + wg*TSTEPS + (TSTEPS-1)] = pred;
    float d = seq[wg*TSTEPS + (TSTEPS-1)] - pred;
    lossacc += d*d;
    ASTORE_F(&losspart[wg], lossacc);
  }
  grid_barrier();
  if (wg == 0) {
    float v = 0.f;
    if (tid < 128) v = ALOAD_F(&losspart[tid]);
    v += __shfl_xor(v, 1);  v += __shfl_xor(v, 2);
    v += __shfl_xor(v, 4);  v += __shfl_xor(v, 8);
    v += __shfl_xor(v, 16); v += __shfl_xor(v, 32);
    if (tid == 0)  pr2[0] = v;
    if (tid == 64) pr2[1] = v;
    __syncthreads();
    if (tid == 0) out[0] = (pr2[0] + pr2[1]) * (1.f/65536.f);
  }
}

extern "C" void kernel_launch(void* const* d_in, const int* in_sizes, int n_in,
                              void* d_out, int out_size, void* d_ws, size_t ws_size,
                              hipStream_t stream)
{
  const float* seq  = (const float*)d_in[0];
  const float* z    = (const float*)d_in[1];
  const float* Wih0 = (const float*)d_in[2];
  const float* Whh0 = (const float*)d_in[3];
  const float* bih0 = (const float*)d_in[4];
  const float* bhh0 = (const float*)d_in[5];
  const float* Wih1 = (const float*)d_in[6];
  const float* Whh1 = (const float*)d_in[7];
  const float* bih1 = (const float*)d_in[8];
  const float* bhh1 = (const float*)d_in[9];
  const float* Wout = (const float*)d_in[10];
  const float* bout = (const float*)d_in[11];
  float* out = (float*)d_out;

  // proven layout (shalf slot now unused)
  char* ws = (char*)d_ws;
  unsigned short* st0 = (unsigned short*)(ws);                    // 256KB @ 0
  unsigned short* st1 = (unsigned short*)(ws + 256*1024);         // 256KB @ 256K
  unsigned* bar   = (unsigned*)(ws + 512*1024);                   // 4KB  @ 512K
  float* predpart = (float*)(ws + 516*1024);                      // 64KB @ 516K
  float* losspart = (float*)(ws + 644*1024);                      // 512B @ 644K

  hipLaunchKernelGGL(init_kernel, dim3(256), dim3(256), 0, stream, z, st0, bar);

  void* args[] = { (void*)&seq, (void*)&z, (void*)&Wih0, (void*)&Whh0, (void*)&bih0, (void*)&bhh0,
                   (void*)&Wih1, (void*)&Whh1, (void*)&bih1, (void*)&bhh1, (void*)&Wout, (void*)&bout,
                   (void*)&out, (void*)&st0, (void*)&st1, (void*)&predpart,
                   (void*)&losspart, (void*)&bar };
  hipLaunchCooperativeKernel((void*)lstm_kernel, dim3(NWG), dim3(NTHR), args, 0u, stream);
}

// Round 14
// 26586.121 us; speedup vs baseline: 1.1388x; 1.1388x over previous
//
#include <hip/hip_runtime.h>
#include <hip/hip_bf16.h>

#define HID 1024
#define BATCH 128
#define TSTEPS 512
#define NWG 128
#define NTHR 512

typedef __bf16 bf16x4 __attribute__((ext_vector_type(4)));
typedef __bf16 bf16x8 __attribute__((ext_vector_type(8)));
typedef float f32x4 __attribute__((ext_vector_type(4)));

#define ASTORE_U(p,v) __hip_atomic_store((p),(v),__ATOMIC_RELAXED,__HIP_MEMORY_SCOPE_AGENT)
#define ASTORE_F(p,v) __hip_atomic_store((p),(v),__ATOMIC_RELAXED,__HIP_MEMORY_SCOPE_AGENT)
#define ALOAD_U(p)    __hip_atomic_load((p),__ATOMIC_RELAXED,__HIP_MEMORY_SCOPE_AGENT)
#define ALOAD_F(p)    __hip_atomic_load((p),__ATOMIC_RELAXED,__HIP_MEMORY_SCOPE_AGENT)
#define ALOAD_ULL(p)  __hip_atomic_load((p),__ATOMIC_RELAXED,__HIP_MEMORY_SCOPE_AGENT)
#define AADD_U(p,v)   __hip_atomic_fetch_add((p),(v),__ATOMIC_RELAXED,__HIP_MEMORY_SCOPE_AGENT)

__device__ __forceinline__ float sigm(float x){ return 1.f/(1.f+__expf(-x)); }

__device__ __forceinline__ bf16x8 cvt8(const float* __restrict__ p){
  bf16x8 r;
  #pragma unroll
  for (int i=0;i<8;i++) r[i] = (__bf16)p[i];
  return r;
}
__device__ __forceinline__ bf16x8 cvt8s(const float* __restrict__ p, float s){
  bf16x8 r;
  #pragma unroll
  for (int i=0;i<8;i++) r[i] = (__bf16)(p[i]*s);
  return r;
}

// init: zero barrier, stage z (proven layout: elem (u,b) at (u>>2)*512+b*4+(u&3)),
// and build w1s = Wih1 as bf16 pre-swizzled into exact MFMA B-frag order:
// frag index f = ((wg*2+ct)*32+kt)*64+lane  ->  16 bytes at w1s+f*8 shorts.
// Row gcr = (c16>>3)*1024 + wg*8 + (c16&7) + ct*2048, cols k0 = kt*32+(lane>>4)*8.
__global__ void init_kernel(const float* __restrict__ z,
                            const float* __restrict__ Wih1src,
                            unsigned short* __restrict__ st0,
                            unsigned short* __restrict__ w1s,
                            unsigned* __restrict__ bar){
  int i = blockIdx.x*blockDim.x + threadIdx.x;     // 524288 threads
  if (i < 1024) bar[i] = 0u;
  if (i < BATCH*HID){
    int blk = i >> 9, rem = i & 511, b = rem >> 2, du = rem & 3;
    st0[i] = __builtin_bit_cast(unsigned short, (__bf16)z[b*HID + blk*4 + du]);
  }
  {
    int lane = i & 63, kt = (i >> 6) & 31, ct = (i >> 11) & 1, wg = i >> 12;
    int c16 = lane & 15;
    int gcr = (c16 >> 3)*HID + (wg << 3) + (c16 & 7) + ct*2048;
    int k0  = (kt << 5) + ((lane >> 4) << 3);
    *reinterpret_cast<bf16x8*>(w1s + (size_t)i*8) = cvt8(Wih1src + (size_t)gcr*HID + k0);
  }
}

// barrier word offsets, each slot in its own 128B line, all < 1024 words (4KB)
#define GRP_CTR(g)  ((g)*32)
#define MID_CTR     256
#define GRP_FLAG(g) (320 + (g)*32)

// 128 WGs x 8 units (round-13 skeleton, PASSED bitwise): h-broadcast halved to
// 32MB/phase. Whh0/Whh1 LDS-resident (128KB). Wih1 streamed from w1s (bf16,
// pre-swizzled, L2-resident, 4-deep ring) -- fixes round 13's unprefetched
// fp32 stream (FETCH 32GB, serialized loads). Wfold rank-1 recomputed (L1-hot).
__global__ __launch_bounds__(NTHR, 2) void lstm_kernel(
    const float* __restrict__ seq,
    const float* __restrict__ z,
    const float* __restrict__ Wih0, const float* __restrict__ Whh0,
    const float* __restrict__ bih0, const float* __restrict__ bhh0,
    const float* __restrict__ Wih1, const float* __restrict__ Whh1,
    const float* __restrict__ bih1, const float* __restrict__ bhh1,
    const float* __restrict__ Wout, const float* __restrict__ bout,
    float* __restrict__ out,
    unsigned short* __restrict__ st0,
    unsigned short* __restrict__ st1,
    const unsigned short* __restrict__ w1s,
    float* __restrict__ predpart,   // [wg][b]
    float* __restrict__ losspart,
    unsigned* __restrict__ bar)
{
  const int tid  = threadIdx.x;
  const int wg   = blockIdx.x;
  const int wid  = tid >> 6;
  const int lane = tid & 63;
  const int u0   = wg << 3;          // owns units [u0,u0+8) in both layers

  __shared__ bf16x8 wlds[2][2][32][64];  // [mat 0=Whh0,1=Whh1][ct][kt][lane] 128KB
  __shared__ float finals2[32*132];      // [col][b], padded stride 132 (16.9KB)
  __shared__ float pr2[2];
  __shared__ float sb0p[32], sb0f[32], sb1[32];

  const float bout_s = bout[0];

  if (tid < 32) {
    int g = tid >> 3, u = tid & 7;
    int gc = g*HID + u0 + u;
    float bp = bih0[gc] + bhh0[gc];
    sb0p[tid] = bp;                       // layer0 bias, t==0 (pred = 0)
    sb0f[tid] = bp + Wih0[gc]*bout_s;     // layer0 bias + folded b_out term
    sb1[tid]  = bih1[gc] + bhh1[gc];
  }

  const int eb  = tid >> 2;
  const int edu = tid & 3;
  const float woutA = Wout[u0 + edu];
  const float woutB = Wout[u0 + 4 + edu];
  float c0A = z[eb*HID + u0 + edu],     c1A = c0A;
  float c0B = z[eb*HID + u0 + 4 + edu], c1B = c0B;
  float lossacc = 0.f;
  float myfull  = 0.f;                    // thread0: full pred sum for batch wg

  const int c16  = lane & 15;
  const int gcr0 = (c16 >> 3)*HID + u0 + (c16 & 7);
  const int ksub = (lane >> 4) << 3;
  const float wih0c0 = Wih0[gcr0];
  const float wih0c1 = Wih0[gcr0 + 2048];

  // resident weights -> LDS (each wave loads its 4 kt-slices)
  {
    #pragma unroll
    for (int ktl=0; ktl<4; ++ktl) {
      int ktg = (wid << 2) + ktl;
      int k0  = (ktg << 5) + ksub;
      wlds[0][0][ktg][lane] = cvt8(Whh0 + (size_t)gcr0*HID + k0);
      wlds[0][1][ktg][lane] = cvt8(Whh0 + (size_t)(gcr0+2048)*HID + k0);
      wlds[1][0][ktg][lane] = cvt8(Whh1 + (size_t)gcr0*HID + k0);
      wlds[1][1][ktg][lane] = cvt8(Whh1 + (size_t)(gcr0+2048)*HID + k0);
    }
  }
  __syncthreads();

  f32x4 accG0[2] = {f32x4{0,0,0,0}, f32x4{0,0,0,0}};
  f32x4 accG1[2] = {f32x4{0,0,0,0}, f32x4{0,0,0,0}};
  unsigned gen = 0;

  // A-frag (M-split, proven): b = wid*16 + (lane&15)
  const int hi2 = (lane >> 4) << 1;
  const int bb4 = ((wid << 4) + c16) << 2;

  auto ldfrag = [&](const unsigned short* __restrict__ src, int kt)->bf16x8{
    const unsigned short* p = src + (size_t)(((kt << 3) + hi2) * 512) + bb4;
    unsigned long long lo64 = ALOAD_ULL((const unsigned long long*)p);
    unsigned long long hi64 = ALOAD_ULL((const unsigned long long*)(p + 512));
    bf16x4 lo = __builtin_bit_cast(bf16x4, lo64);
    bf16x4 hi = __builtin_bit_cast(bf16x4, hi64);
    return __builtin_shufflevector(lo, hi, 0,1,2,3,4,5,6,7);
  };

  // streamed Wih1 B-frag: plain cached 16B load (read-only, L2-resident)
  auto ldw = [&](int ct, int kt)->bf16x8{
    return *reinterpret_cast<const bf16x8*>(
        w1s + (size_t)((((wg << 1) + ct) << 5 | kt) << 6 | lane) * 8);
  };

  // MODE 0 (prologue): accA <- Whh0 (LDS), accB <- Whh1 (LDS)
  // MODE 1 (phase A):  accA <- Wih1 (w1s stream, 4-deep ring), accB <- Whh0 (LDS)
  // MODE 2 (phase B):  accA <- Wfold (rank-1 recompute), accB <- Whh1 (LDS)
  auto do_pass = [&](const unsigned short* __restrict__ src, int mode,
                     f32x4* accA, f32x4* accB){
    bf16x8 af[8];
    #pragma unroll
    for (int i=0;i<8;i++) af[i] = ldfrag(src, i);
    bf16x8 wf[4][2];
    if (mode == 1) {
      #pragma unroll
      for (int k=0;k<4;k++){ wf[k][0] = ldw(0,k); wf[k][1] = ldw(1,k); }
    }
    #pragma unroll
    for (int kt=0; kt<32; ++kt){
      bf16x8 a = af[kt & 7];
      int k0 = (kt << 5) + ksub;
      if (mode == 0) {
        accA[0] = __builtin_amdgcn_mfma_f32_16x16x32_bf16(a, wlds[0][0][kt][lane], accA[0], 0, 0, 0);
        accA[1] = __builtin_amdgcn_mfma_f32_16x16x32_bf16(a, wlds[0][1][kt][lane], accA[1], 0, 0, 0);
        accB[0] = __builtin_amdgcn_mfma_f32_16x16x32_bf16(a, wlds[1][0][kt][lane], accB[0], 0, 0, 0);
        accB[1] = __builtin_amdgcn_mfma_f32_16x16x32_bf16(a, wlds[1][1][kt][lane], accB[1], 0, 0, 0);
      } else if (mode == 1) {
        accA[0] = __builtin_amdgcn_mfma_f32_16x16x32_bf16(a, wf[kt&3][0], accA[0], 0, 0, 0);
        accA[1] = __builtin_amdgcn_mfma_f32_16x16x32_bf16(a, wf[kt&3][1], accA[1], 0, 0, 0);
        accB[0] = __builtin_amdgcn_mfma_f32_16x16x32_bf16(a, wlds[0][0][kt][lane], accB[0], 0, 0, 0);
        accB[1] = __builtin_amdgcn_mfma_f32_16x16x32_bf16(a, wlds[0][1][kt][lane], accB[1], 0, 0, 0);
        if (kt < 28) { wf[kt&3][0] = ldw(0, kt+4); wf[kt&3][1] = ldw(1, kt+4); }
      } else {
        bf16x8 wf0 = cvt8s(Wout + k0, wih0c0);
        bf16x8 wf1 = cvt8s(Wout + k0, wih0c1);
        accA[0] = __builtin_amdgcn_mfma_f32_16x16x32_bf16(a, wf0, accA[0], 0, 0, 0);
        accA[1] = __builtin_amdgcn_mfma_f32_16x16x32_bf16(a, wf1, accA[1], 0, 0, 0);
        accB[0] = __builtin_amdgcn_mfma_f32_16x16x32_bf16(a, wlds[1][0][kt][lane], accB[0], 0, 0, 0);
        accB[1] = __builtin_amdgcn_mfma_f32_16x16x32_bf16(a, wlds[1][1][kt][lane], accB[1], 0, 0, 0);
      }
      if (kt < 24) af[kt & 7] = ldfrag(src, kt + 8);   // refill after last use
    }
  };

  // acc final: scatter to finals2[col][b] (+bias), one sync.
  auto publish = [&](f32x4* acc, const float* sbias){
    #pragma unroll
    for (int ct=0; ct<2; ++ct){
      int c = (ct << 4) + c16;
      float bias = sbias[c];
      int base = c*132 + (wid << 4) + ((lane >> 4) << 2);
      #pragma unroll
      for (int e=0;e<4;e++) finals2[base + e] = acc[ct][e] + bias;
      acc[ct] = f32x4{0,0,0,0};
    }
    __syncthreads();
  };

  auto elementwise = [&](float& cA, float& cB, unsigned short* __restrict__ stdst,
                         bool dopred){
    float giA = finals2[(edu    )*132 + eb];
    float gfA = finals2[(edu+ 8 )*132 + eb];
    float ggA = finals2[(edu+16 )*132 + eb];
    float goA = finals2[(edu+24 )*132 + eb];
    float giB = finals2[(edu+ 4 )*132 + eb];
    float gfB = finals2[(edu+12 )*132 + eb];
    float ggB = finals2[(edu+20 )*132 + eb];
    float goB = finals2[(edu+28 )*132 + eb];
    cA = sigm(gfA)*cA + sigm(giA)*tanhf(ggA);
    float hA = sigm(goA)*tanhf(cA);
    cB = sigm(gfB)*cB + sigm(giB)*tanhf(cB*0.f + ggB);
    float hB = sigm(goB)*tanhf(cB);
    unsigned hA16 = (unsigned)__builtin_bit_cast(unsigned short, (__bf16)hA);
    unsigned hB16 = (unsigned)__builtin_bit_cast(unsigned short, (__bf16)hB);
    unsigned nA = (unsigned)__shfl_xor((int)hA16, 1);
    unsigned nB = (unsigned)__shfl_xor((int)hB16, 1);
    if (!(tid & 1)) {
      unsigned wordA = hA16 | (nA << 16);   // units edu,edu+1 -> block 2wg
      unsigned wordB = hB16 | (nB << 16);   // units 4+edu,5+edu -> block 2wg+1
      ASTORE_U((unsigned*)(stdst + (2*wg  )*512 + eb*4 + edu), wordA);
      ASTORE_U((unsigned*)(stdst + (2*wg+1)*512 + eb*4 + edu), wordB);
    }
    if (dopred){
      float pv = hA*woutA + hB*woutB;
      pv += __shfl_xor(pv, 1);
      pv += __shfl_xor(pv, 2);
      if (edu == 0) ASTORE_F(&predpart[wg*128 + eb], pv);
    }
  };

  // proven barrier (8 groups x 16 WGs): padded counters, fan-out release, sc1.
  auto grid_barrier = [&](){
    __syncthreads();                       // drains vmcnt -> sc1 stores at L3
    ++gen;
    if (tid == 0) {
      unsigned old = AADD_U(&bar[GRP_CTR(wg & 7)], 1u);
      if (old == gen*16u - 1u) {
        unsigned r = AADD_U(&bar[MID_CTR], 1u);
        if (r == gen*8u - 1u) {
          #pragma unroll
          for (int g2=0; g2<8; ++g2) ASTORE_U(&bar[GRP_FLAG(g2)], gen);
        }
      }
      while (ALOAD_U(&bar[GRP_FLAG(wg & 7)]) < gen)
        __builtin_amdgcn_s_sleep(4);
    }
    __syncthreads();
  };

  // ---- prologue ----
  do_pass(st0, 0, accG0, accG1);
  grid_barrier();                          // all WGs consumed z-staging
  publish(accG0, sb0p);
  elementwise(c0A, c0B, st0, false);       // h0[0] -> st0
  grid_barrier();                          // publish h0[0]

  for (int t=0; t<TSTEPS; ++t) {
    // ---- Phase A: gates1[t] (h0@Wih1 streamed); gates0[t+1] h0-part ----
    do_pass(st0, 1, accG1, accG0);
    publish(accG1, sb1);
    if (t > 0 && tid == 0) {               // finalize pred[t-1] (batch wg)
      float pred = myfull + bout_s;
      out[1 + wg*TSTEPS + (t-1)] = pred;
      float d = seq[wg*TSTEPS + (t-1)] - pred;
      lossacc += d*d;
    }
    elementwise(c1A, c1B, st1, true);      // h1[t] + pred partials
    grid_barrier();                        // publish h1[t], predpart

    // ---- Phase B: gates0[t+1] (h1@Wfold rank-1); gates1[t+1] h1-part ----
    float hred = 0.f;
    if (tid < 128)
      hred = ALOAD_F(&predpart[tid*128 + wg]);   // early load, all 128 partials
    do_pass(st1, 2, accG0, accG1);
    hred += __shfl_xor(hred, 1);  hred += __shfl_xor(hred, 2);
    hred += __shfl_xor(hred, 4);  hred += __shfl_xor(hred, 8);
    hred += __shfl_xor(hred, 16); hred += __shfl_xor(hred, 32);
    if (tid == 0)  pr2[0] = hred;
    if (tid == 64) pr2[1] = hred;
    publish(accG0, sb0f);                  // internal sync publishes pr2 to tid0
    if (tid == 0) myfull = pr2[0] + pr2[1];
    elementwise(c0A, c0B, st0, false);     // h0[t+1]
    grid_barrier();                        // publish h0[t+1]
  }

  // ---- epilogue: last pred + loss ----
  if (tid == 0) {
    float pred = myfull + bout_s;
    out[1 + wg*TSTEPS + (TSTEPS-1)] = pred;
    float d = seq[wg*TSTEPS + (TSTEPS-1)] - pred;
    lossacc += d*d;
    ASTORE_F(&losspart[wg], lossacc);
  }
  grid_barrier();
  if (wg == 0) {
    float v = 0.f;
    if (tid < 128) v = ALOAD_F(&losspart[tid]);
    v += __shfl_xor(v, 1);  v += __shfl_xor(v, 2);
    v += __shfl_xor(v, 4);  v += __shfl_xor(v, 8);
    v += __shfl_xor(v, 16); v += __shfl_xor(v, 32);
    if (tid == 0)  pr2[0] = v;
    if (tid == 64) pr2[1] = v;
    __syncthreads();
    if (tid == 0) out[0] = (pr2[0] + pr2[1]) * (1.f/65536.f);
  }
}

extern "C" void kernel_launch(void* const* d_in, const int* in_sizes, int n_in,
                              void* d_out, int out_size, void* d_ws, size_t ws_size,
                              hipStream_t stream)
{
  const float* seq  = (const float*)d_in[0];
  const float* z    = (const float*)d_in[1];
  const float* Wih0 = (const float*)d_in[2];
  const float* Whh0 = (const float*)d_in[3];
  const float* bih0 = (const float*)d_in[4];
  const float* bhh0 = (const float*)d_in[5];
  const float* Wih1 = (const float*)d_in[6];
  const float* Whh1 = (const float*)d_in[7];
  const float* bih1 = (const float*)d_in[8];
  const float* bhh1 = (const float*)d_in[9];
  const float* Wout = (const float*)d_in[10];
  const float* bout = (const float*)d_in[11];
  float* out = (float*)d_out;

  char* ws = (char*)d_ws;
  unsigned short* st0 = (unsigned short*)(ws);                    // 256KB @ 0
  unsigned short* st1 = (unsigned short*)(ws + 256*1024);         // 256KB @ 256K
  unsigned* bar   = (unsigned*)(ws + 512*1024);                   // 4KB  @ 512K
  float* predpart = (float*)(ws + 516*1024);                      // 64KB @ 516K
  float* losspart = (float*)(ws + 580*1024);                      // 512B @ 580K
  unsigned short* w1s = (unsigned short*)(ws + 1024*1024);        // 8MB @ 1M

  hipLaunchKernelGGL(init_kernel, dim3(2048), dim3(256), 0, stream, z, Wih1, st0, w1s, bar);

  void* args[] = { (void*)&seq, (void*)&z, (void*)&Wih0, (void*)&Whh0, (void*)&bih0, (void*)&bhh0,
                   (void*)&Wih1, (void*)&Whh1, (void*)&bih1, (void*)&bhh1, (void*)&Wout, (void*)&bout,
                   (void*)&out, (void*)&st0, (void*)&st1, (void*)&w1s, (void*)&predpart,
                   (void*)&losspart, (void*)&bar };
  hipLaunchCooperativeKernel((void*)lstm_kernel, dim3(NWG), dim3(NTHR), args, 0u, stream);
}

// Round 15
// 6493.859 us; speedup vs baseline: 4.6621x; 4.0940x over previous
//
#include <hip/hip_runtime.h>
#include <hip/hip_bf16.h>

#define HID 1024
#define BATCH 128
#define TSTEPS 512
#define NWG 256
#define NTHR 512

typedef __bf16 bf16x4 __attribute__((ext_vector_type(4)));
typedef __bf16 bf16x8 __attribute__((ext_vector_type(8)));
typedef float f32x4 __attribute__((ext_vector_type(4)));

#define ASTORE_U(p,v) __hip_atomic_store((p),(v),__ATOMIC_RELAXED,__HIP_MEMORY_SCOPE_AGENT)
#define ASTORE_F(p,v) __hip_atomic_store((p),(v),__ATOMIC_RELAXED,__HIP_MEMORY_SCOPE_AGENT)
#define ALOAD_U(p)    __hip_atomic_load((p),__ATOMIC_RELAXED,__HIP_MEMORY_SCOPE_AGENT)
#define ALOAD_F(p)    __hip_atomic_load((p),__ATOMIC_RELAXED,__HIP_MEMORY_SCOPE_AGENT)
#define ALOAD_ULL(p)  __hip_atomic_load((p),__ATOMIC_RELAXED,__HIP_MEMORY_SCOPE_AGENT)
#define AADD_U(p,v)   __hip_atomic_fetch_add((p),(v),__ATOMIC_RELAXED,__HIP_MEMORY_SCOPE_AGENT)

__device__ __forceinline__ float sigm(float x){ return 1.f/(1.f+__expf(-x)); }

__device__ __forceinline__ bf16x8 cvt8s(const float* __restrict__ p, float s){
  bf16x8 r;
  #pragma unroll
  for (int i=0;i<8;i++) r[i] = (__bf16)(p[i]*s);
  return r;
}

// init: zero barrier; stage zst = bf16(127*z) in the proven layout
// (elem (u,b) at (u>>2)*512 + b*4 + (u&3)). st0q/st1q (int8) need no init:
// fully written before first read.
__global__ void init_kernel(const float* __restrict__ z,
                            unsigned short* __restrict__ zst,
                            unsigned* __restrict__ bar){
  int i = blockIdx.x*blockDim.x + threadIdx.x;     // 65536 threads
  if (i < 1024) bar[i] = 0u;
  for (int idx = i; idx < BATCH*HID; idx += 65536){
    int blk = idx >> 9, rem = idx & 511, b = rem >> 2, du = rem & 3;
    zst[idx] = __builtin_bit_cast(unsigned short,
                 (__bf16)(z[b*HID + blk*4 + du] * 127.f));
  }
}

// barrier word offsets, each slot in its own 128B line, all < 1024 words (4KB)
#define GRP_CTR(g)  ((g)*32)
#define MID_CTR     256
#define GRP_FLAG(g) (320 + (g)*32)

// R12 structure (proven 6.44ms) + int8 h-staging: M-split waves (full K/wave,
// no cross-wave reduction), weights in LDS pre-scaled by 1/127 (dequant folded),
// h exchanged as int8 (q=rint(127h), |h|<1 strict) -> 32MB/phase on-die reads.
// Prologue reads zst = bf16(127z): (127z)@(W/127) = z@W (unbounded-z safe).
__global__ __launch_bounds__(NTHR, 2) void lstm_kernel(
    const float* __restrict__ seq,
    const float* __restrict__ z,
    const float* __restrict__ Wih0, const float* __restrict__ Whh0,
    const float* __restrict__ bih0, const float* __restrict__ bhh0,
    const float* __restrict__ Wih1, const float* __restrict__ Whh1,
    const float* __restrict__ bih1, const float* __restrict__ bhh1,
    const float* __restrict__ Wout, const float* __restrict__ bout,
    float* __restrict__ out,
    unsigned char* __restrict__ st0q,
    unsigned char* __restrict__ st1q,
    const unsigned short* __restrict__ zst,
    float* __restrict__ predpart,   // [wg][b]
    float* __restrict__ shalf,      // [b] upper-half partial sums
    float* __restrict__ losspart,
    unsigned* __restrict__ bar)
{
  const int tid  = threadIdx.x;
  const int wg   = blockIdx.x;
  const int wid  = tid >> 6;
  const int lane = tid & 63;
  const int u0   = wg << 2;          // owns units [u0,u0+4) in both layers

  // mats: 0=Whh0, 1=Wih1, 2=Whh1, 3=Wfold  (ALL pre-scaled by 1/127)
  __shared__ bf16x8 wlds[4][32][64];  // 128KB
  __shared__ float finals2[16*132];   // [col][b], padded stride 132
  __shared__ float pr2[2];
  __shared__ float sb0p[16], sb0f[16], sb1[16];

  const float bout_s = bout[0];
  const float ISC = 1.f/127.f;

  if (tid < 16) {
    int g = tid >> 2, du = tid & 3;
    int gc = g*HID + u0 + du;
    float bp = bih0[gc] + bhh0[gc];
    sb0p[tid] = bp;                       // biases are NOT scaled (add after matmul)
    sb0f[tid] = bp + Wih0[gc]*bout_s;
    sb1[tid]  = bih1[gc] + bhh1[gc];
  }

  const int eb  = tid >> 2;
  const int edu = tid & 3;
  const float wout_u = Wout[u0 + edu];
  float c0 = z[eb*HID + u0 + edu];
  float c1 = c0;
  float lossacc = 0.f;
  float myhalf  = 0.f;                    // thread0 of wg<128: lower-half pred sum

  // ---- weights -> LDS, pre-swizzled B-frags, scaled by 1/127 ----
  const int bcol = lane & 15;
  const int gcol = (bcol >> 2)*HID + u0 + (bcol & 3);
  const int ksub = (lane >> 4) << 3;
  {
    const float wih0c = Wih0[gcol];
    #pragma unroll
    for (int ktl=0; ktl<4; ++ktl) {
      int k0  = (wid << 7) + (ktl << 5) + ksub;
      int ktg = (wid << 2) + ktl;
      wlds[0][ktg][lane] = cvt8s(Whh0 + gcol*HID + k0, ISC);
      wlds[1][ktg][lane] = cvt8s(Wih1 + gcol*HID + k0, ISC);
      wlds[2][ktg][lane] = cvt8s(Whh1 + gcol*HID + k0, ISC);
      wlds[3][ktg][lane] = cvt8s(Wout + k0, wih0c * ISC);   // rank-1 fold, scaled
    }
  }
  __syncthreads();

  f32x4 accG0{0,0,0,0}, accG1{0,0,0,0};
  unsigned gen = 0;

  // A-frag addressing (proven): b = wid*16 + (lane&15); k = kt*32+(lane>>4)*8+e
  const int hi2 = (lane >> 4) << 1;
  const int bb4 = ((wid << 4) + (lane & 15)) << 2;

  // bf16 z-frag (prologue only)
  auto ldfragz = [&](int kt)->bf16x8{
    const unsigned short* p = zst + (size_t)(((kt << 3) + hi2) * 512) + bb4;
    unsigned long long lo64 = ALOAD_ULL((const unsigned long long*)p);
    unsigned long long hi64 = ALOAD_ULL((const unsigned long long*)(p + 512));
    bf16x4 lo = __builtin_bit_cast(bf16x4, lo64);
    bf16x4 hi = __builtin_bit_cast(bf16x4, hi64);
    return __builtin_shufflevector(lo, hi, 0,1,2,3,4,5,6,7);
  };

  // int8 frag: two 4B sc1 loads (block and block+1), dequant at use.
  auto ld_i8 = [&](const unsigned char* __restrict__ src, int kt,
                   unsigned& lo, unsigned& hi){
    const unsigned char* p = src + (size_t)(((kt << 3) + hi2) * 512) + bb4;
    lo = ALOAD_U((const unsigned*)p);
    hi = ALOAD_U((const unsigned*)(p + 512));
  };
  auto dq8 = [&](unsigned lo, unsigned hi)->bf16x8{
    bf16x8 r;
    #pragma unroll
    for (int i=0;i<4;i++){
      int q0 = (int)(lo << (24 - 8*i)) >> 24;   // sign-extend byte i
      int q1 = (int)(hi << (24 - 8*i)) >> 24;
      r[i]   = (__bf16)(float)q0;               // exact: |q|<=127 in bf16
      r[4+i] = (__bf16)(float)q1;
    }
    return r;
  };

  // prologue pass (bf16 zst, runs once)
  auto do_pass_pro = [&](int matA, int matB, f32x4& accA, f32x4& accB){
    #pragma unroll
    for (int kt=0; kt<32; ++kt){
      bf16x8 a = ldfragz(kt);
      accA = __builtin_amdgcn_mfma_f32_16x16x32_bf16(a, wlds[matA][kt][lane], accA, 0, 0, 0);
      accB = __builtin_amdgcn_mfma_f32_16x16x32_bf16(a, wlds[matB][kt][lane], accB, 0, 0, 0);
    }
  };

  // main pass: 8-deep raw-dword ring (16 VGPR), dequant before MFMA.
  auto do_pass = [&](const unsigned char* __restrict__ src, int matA, int matB,
                     f32x4& accA, f32x4& accB){
    unsigned rl[8], rh[8];
    #pragma unroll
    for (int i=0;i<8;i++) ld_i8(src, i, rl[i], rh[i]);
    #pragma unroll
    for (int kt=0; kt<32; ++kt){
      bf16x8 a = dq8(rl[kt & 7], rh[kt & 7]);
      accA = __builtin_amdgcn_mfma_f32_16x16x32_bf16(a, wlds[matA][kt][lane], accA, 0, 0, 0);
      accB = __builtin_amdgcn_mfma_f32_16x16x32_bf16(a, wlds[matB][kt][lane], accB, 0, 0, 0);
      if (kt < 24) ld_i8(src, kt + 8, rl[kt & 7], rh[kt & 7]);
    }
  };

  // acc is FINAL (full K per wave): scatter to finals2[col][b] (+bias), one sync.
  auto publish = [&](f32x4& acc, const float* sbias){
    float bias = sbias[lane & 15];
    int base = (lane & 15)*132 + (wid << 4) + ((lane >> 4) << 2);
    #pragma unroll
    for (int e=0;e<4;e++) finals2[base + e] = acc[e] + bias;
    __syncthreads();
    acc = f32x4{0,0,0,0};
  };

  // elementwise + int8 quant-pack-store (4 threads -> one dword)
  auto elementwise = [&](float& c, unsigned char* __restrict__ stdst, bool dopred){
    float gi = finals2[(edu   )*132 + eb];
    float gf = finals2[(edu+ 4)*132 + eb];
    float gg = finals2[(edu+ 8)*132 + eb];
    float go = finals2[(edu+12)*132 + eb];
    float fi = sigm(gi), ff = sigm(gf), fo = sigm(go);
    c = ff*c + fi*tanhf(gg);
    float h = fo*tanhf(c);                         // |h| < 1 strictly
    int q = (int)__builtin_rintf(h * 127.f);       // q in [-127,127]
    unsigned b8 = ((unsigned)q & 0xFFu) << (edu*8);
    b8 |= (unsigned)__shfl_xor((int)b8, 1);
    b8 |= (unsigned)__shfl_xor((int)b8, 2);
    if (edu == 0)
      ASTORE_U((unsigned*)(stdst + wg*512 + (eb << 2)), b8);
    if (dopred){
      float pv = h * wout_u;                       // fp32 pred partial (pre-quant h)
      pv += __shfl_xor(pv, 1);
      pv += __shfl_xor(pv, 2);
      if (edu == 0) ASTORE_F(&predpart[wg*128 + eb], pv);
    }
  };

  // proven barrier: padded counters, fan-out release, sc1 protocol.
  auto grid_barrier = [&](){
    __syncthreads();                       // drains vmcnt -> sc1 stores at L3
    ++gen;
    if (tid == 0) {
      unsigned old = AADD_U(&bar[GRP_CTR(wg & 7)], 1u);
      if (old == gen*32u - 1u) {
        unsigned r = AADD_U(&bar[MID_CTR], 1u);
        if (r == gen*8u - 1u) {
          #pragma unroll
          for (int g2=0; g2<8; ++g2) ASTORE_U(&bar[GRP_FLAG(g2)], gen);
        }
      }
      while (ALOAD_U(&bar[GRP_FLAG(wg & 7)]) < gen)
        __builtin_amdgcn_s_sleep(4);
    }
    __syncthreads();
  };

  // ---- prologue: accG0 = z@Whh0 (gates0[0]); accG1 = z@Whh1 (carry) ----
  do_pass_pro(0, 2, accG0, accG1);
  grid_barrier();
  publish(accG0, sb0p);
  elementwise(c0, st0q, false);            // h0[0] -> st0q (int8)
  grid_barrier();                          // publish h0[0]

  for (int t=0; t<TSTEPS; ++t) {
    // ---- Phase A: gates1[t] completes (h0@Wih1); gates0[t+1] h0-part (h0@Whh0) ----
    do_pass(st0q, 1, 0, accG1, accG0);
    float oh = 0.f;
    if (t > 0 && wg < BATCH && tid == 0) oh = ALOAD_F(&shalf[wg]);   // early load
    publish(accG1, sb1);
    if (t > 0 && wg < BATCH && tid == 0) {
      float pred = myhalf + oh + bout_s;                   // finalize pred[t-1]
      out[1 + wg*TSTEPS + (t-1)] = pred;
      float d = seq[wg*TSTEPS + (t-1)] - pred;
      lossacc += d*d;
    }
    elementwise(c1, st1q, true);           // h1[t] + pred partials
    grid_barrier();                        // publish h1[t], predpart

    // ---- Phase B: gates0[t+1] completes (h1@Wfold); gates1[t+1] h1-part (h1@Whh1) ----
    float hred = 0.f;
    if (tid < 128)
      hred = ALOAD_F(&predpart[((wg >> 7)*128 + tid)*128 + (wg & 127)]);  // early
    do_pass(st1q, 3, 2, accG0, accG1);
    hred += __shfl_xor(hred, 1);  hred += __shfl_xor(hred, 2);
    hred += __shfl_xor(hred, 4);  hred += __shfl_xor(hred, 8);
    hred += __shfl_xor(hred, 16); hred += __shfl_xor(hred, 32);
    if (tid == 0)  pr2[0] = hred;
    if (tid == 64) pr2[1] = hred;
    publish(accG0, sb0f);                  // internal sync publishes pr2 to tid0
    if (tid == 0) {
      float hs = pr2[0] + pr2[1];
      if (wg >= BATCH) ASTORE_F(&shalf[wg - BATCH], hs);
      else             myhalf = hs;
    }
    elementwise(c0, st0q, false);          // h0[t+1]
    grid_barrier();                        // publish h0[t+1], shalf
  }

  // ---- epilogue: last pred + loss ----
  if (wg < BATCH && tid == 0) {
    float oh2 = ALOAD_F(&shalf[wg]);
    float pred = myhalf + oh2 + bout_s;
    out[1 + wg*TSTEPS + (TSTEPS-1)] = pred;
    float d = seq[wg*TSTEPS + (TSTEPS-1)] - pred;
    lossacc += d*d;
    ASTORE_F(&losspart[wg], lossacc);
  }
  grid_barrier();
  if (wg == 0) {
    float v = 0.f;
    if (tid < BATCH) v = ALOAD_F(&losspart[tid]);
    v += __shfl_xor(v, 1);  v += __shfl_xor(v, 2);
    v += __shfl_xor(v, 4);  v += __shfl_xor(v, 8);
    v += __shfl_xor(v, 16); v += __shfl_xor(v, 32);
    if (tid == 0)  pr2[0] = v;
    if (tid == 64) pr2[1] = v;
    __syncthreads();
    if (tid == 0) out[0] = (pr2[0] + pr2[1]) * (1.f/65536.f);
  }
}

extern "C" void kernel_launch(void* const* d_in, const int* in_sizes, int n_in,
                              void* d_out, int out_size, void* d_ws, size_t ws_size,
                              hipStream_t stream)
{
  const float* seq  = (const float*)d_in[0];
  const float* z    = (const float*)d_in[1];
  const float* Wih0 = (const float*)d_in[2];
  const float* Whh0 = (const float*)d_in[3];
  const float* bih0 = (const float*)d_in[4];
  const float* bhh0 = (const float*)d_in[5];
  const float* Wih1 = (const float*)d_in[6];
  const float* Whh1 = (const float*)d_in[7];
  const float* bih1 = (const float*)d_in[8];
  const float* bhh1 = (const float*)d_in[9];
  const float* Wout = (const float*)d_in[10];
  const float* bout = (const float*)d_in[11];
  float* out = (float*)d_out;

  // proven <=645KB footprint
  char* ws = (char*)d_ws;
  unsigned char*  st0q = (unsigned char*)(ws);                    // 128KB @ 0
  unsigned char*  st1q = (unsigned char*)(ws + 128*1024);         // 128KB @ 128K
  unsigned short* zst  = (unsigned short*)(ws + 256*1024);        // 256KB @ 256K
  unsigned* bar   = (unsigned*)(ws + 512*1024);                   // 4KB  @ 512K
  float* predpart = (float*)(ws + 516*1024);                      // 128KB @ 516K
  float* shalf    = (float*)(ws + 644*1024);                      // 512B @ 644K
  float* losspart = (float*)(ws + 644*1024 + 512);                // 512B

  hipLaunchKernelGGL(init_kernel, dim3(256), dim3(256), 0, stream, z, zst, bar);

  void* args[] = { (void*)&seq, (void*)&z, (void*)&Wih0, (void*)&Whh0, (void*)&bih0, (void*)&bhh0,
                   (void*)&Wih1, (void*)&Whh1, (void*)&bih1, (void*)&bhh1, (void*)&Wout, (void*)&bout,
                   (void*)&out, (void*)&st0q, (void*)&st1q, (void*)&zst, (void*)&predpart,
                   (void*)&shalf, (void*)&losspart, (void*)&bar };
  hipLaunchCooperativeKernel((void*)lstm_kernel, dim3(NWG), dim3(NTHR), args, 0u, stream);
}